// Round 8
// baseline (226.342 us; speedup 1.0000x reference)
//
#include <hip/hip_runtime.h>

typedef unsigned short ushort_t;
typedef __attribute__((ext_vector_type(8))) __bf16 bf16x8;
typedef __attribute__((ext_vector_type(4))) short short4v;
typedef __attribute__((ext_vector_type(4))) float floatx4;

#define AS1 __attribute__((address_space(1)))
#define AS3 __attribute__((address_space(3)))

#define D_MODEL 1024
#define NH 16
#define DKH 64
#define SEQ 2048
#define NB 2
#define MTOT (NB * SEQ)

// log2(e) / sqrt(dk) folded into Q at projection time
#define QSCALE 0.18033688011112042f

// converted-region segment offsets (elements), input order x,Wq,bq,Wk,bk,Wv,bv,Wo,bo
#define OFF_X   0u
#define OFF_WQ  4194304u
#define OFF_BQ  5242880u
#define OFF_WK  5243904u
#define OFF_BK  6292480u
#define OFF_WV  6293504u
#define OFF_BV  7342080u
#define OFF_WO  7343104u
#define OFF_BO  8391680u
#define CVT_TOT 8392704u

// K=16 MFMA (gfx90a-era builtin, present on gfx950 — device pass of r7 compiled
// it). P^T exits QK^T's C-layout exactly in this op's B-fragment layout
// (lane holds k=quad*4+r, col=l15) -> PV needs no LDS round-trip.
// NOTE: do NOT gate on __has_builtin — it returns false for aux-target
// builtins in the HIP host pass and selects a broken fallback.
#define MFMA16(a, b, c) __builtin_amdgcn_mfma_f32_16x16x16bf16_1k((a), (b), (c), 0, 0, 0)

__device__ __forceinline__ float bf2f(ushort_t u) {
    union { unsigned u; float f; } v; v.u = ((unsigned)u) << 16; return v.f;
}
__device__ __forceinline__ ushort_t f2bf(float f) {
    union { float f; unsigned u; } v; v.f = f;
    unsigned r = v.u + 0x7FFFu + ((v.u >> 16) & 1u);  // RNE
    return (ushort_t)(r >> 16);
}
// pack two fp32 -> two bf16 (RNE): low half = bf(a), high = bf(b)
__device__ __forceinline__ unsigned pack2bf(float a, float b) {
    unsigned ua = __float_as_uint(a), ub = __float_as_uint(b);
    ua = ua + 0x7FFFu + ((ua >> 16) & 1u);
    ub = ub + 0x7FFFu + ((ub >> 16) & 1u);
    return __builtin_amdgcn_perm(ub, ua, 0x07060302);
}
__device__ __forceinline__ short4v pack4bf(floatx4 v) {
    union { uint2 u; short4v s; } cv;
    cv.u.x = pack2bf(v[0], v[1]);
    cv.u.y = pack2bf(v[2], v[3]);
    return cv.s;
}

// ---------- convert all fp32 inputs into one contiguous bf16 region ----------
__global__ __launch_bounds__(256) void convert_kernel(
    const float* __restrict__ x,  const float* __restrict__ wq, const float* __restrict__ bq_,
    const float* __restrict__ wk, const float* __restrict__ bk_, const float* __restrict__ wv,
    const float* __restrict__ bv_, const float* __restrict__ wo, const float* __restrict__ bo_,
    ushort_t* __restrict__ dst)
{
    const unsigned idx = ((unsigned)blockIdx.x * 256u + threadIdx.x) * 4u;
    if (idx >= CVT_TOT) return;
    const float* src; unsigned off;
    if      (idx < OFF_WQ) { src = x;   off = idx; }
    else if (idx < OFF_BQ) { src = wq;  off = idx - OFF_WQ; }
    else if (idx < OFF_WK) { src = bq_; off = idx - OFF_BQ; }
    else if (idx < OFF_BK) { src = wk;  off = idx - OFF_WK; }
    else if (idx < OFF_WV) { src = bk_; off = idx - OFF_BK; }
    else if (idx < OFF_BV) { src = wv;  off = idx - OFF_WV; }
    else if (idx < OFF_WO) { src = bv_; off = idx - OFF_BV; }
    else if (idx < OFF_BO) { src = wo;  off = idx - OFF_WO; }
    else                   { src = bo_; off = idx - OFF_BO; }
    float4 v = *reinterpret_cast<const float4*>(src + off);
    uint2 p;
    p.x = pack2bf(v.x, v.y);
    p.y = pack2bf(v.z, v.w);
    *reinterpret_cast<uint2*>(dst + idx) = p;
}

// GEMM core, BK=64 via two unpadded [128][32] sub-tiles (m97 bank pattern kept,
// global_load_lds contiguity kept). 32 MFMA per barrier pair, 16 iters at K=1024.
// lds layout: A0 [0,4096) A1 [4096,8192) B0 [8192,12288) B1 [12288,16384)
__device__ __forceinline__ void gemm_core(
    const ushort_t* __restrict__ X, const ushort_t* __restrict__ W,
    int m0, int n0, ushort_t* lds, floatx4 acc[4][4])
{
    const int tid = threadIdx.x;
    const int lane = tid & 63, wv = tid >> 6;
    const int wm = (wv >> 1) * 64, wn = (wv & 1) * 64;
    const int l15 = lane & 15, quad = lane >> 4;
    const floatx4 z4 = {0.f, 0.f, 0.f, 0.f};
#pragma unroll
    for (int i = 0; i < 4; ++i)
#pragma unroll
        for (int j = 0; j < 4; ++j) acc[i][j] = z4;
    const int lrow = lane >> 2;        // 0..15
    const int lcol = (lane & 3) * 8;   // 0,8,16,24
    const ushort_t* gA = X + (size_t)(m0 + lrow) * D_MODEL + lcol;
    const ushort_t* gB = W + (size_t)(n0 + lrow) * D_MODEL + lcol;
    for (int k0 = 0; k0 < D_MODEL; k0 += 64) {
        __syncthreads();  // prior frag reads done before overwrite
#pragma unroll
        for (int j = 0; j < 2; ++j) {
            const int r0 = (wv * 2 + j) * 16;  // wave-uniform
            __builtin_amdgcn_global_load_lds(
                (const AS1 unsigned*)(gA + (size_t)r0 * D_MODEL + k0),
                (AS3 unsigned*)(lds + r0 * 32), 16, 0, 0);
            __builtin_amdgcn_global_load_lds(
                (const AS1 unsigned*)(gA + (size_t)r0 * D_MODEL + k0 + 32),
                (AS3 unsigned*)(lds + 4096 + r0 * 32), 16, 0, 0);
            __builtin_amdgcn_global_load_lds(
                (const AS1 unsigned*)(gB + (size_t)r0 * D_MODEL + k0),
                (AS3 unsigned*)(lds + 8192 + r0 * 32), 16, 0, 0);
            __builtin_amdgcn_global_load_lds(
                (const AS1 unsigned*)(gB + (size_t)r0 * D_MODEL + k0 + 32),
                (AS3 unsigned*)(lds + 12288 + r0 * 32), 16, 0, 0);
        }
        asm volatile("s_waitcnt vmcnt(0)" ::: "memory");
        __syncthreads();
#pragma unroll
        for (int ks = 0; ks < 2; ++ks) {
            const ushort_t* A = lds + ks * 4096;
            const ushort_t* B = lds + 8192 + ks * 4096;
            bf16x8 af[4], bfr[4];
#pragma unroll
            for (int i = 0; i < 4; ++i)
                af[i] = *reinterpret_cast<const bf16x8*>(A + (wm + i * 16 + l15) * 32 + quad * 8);
#pragma unroll
            for (int j = 0; j < 4; ++j)
                bfr[j] = *reinterpret_cast<const bf16x8*>(B + (wn + j * 16 + l15) * 32 + quad * 8);
#pragma unroll
            for (int i = 0; i < 4; ++i)
#pragma unroll
                for (int j = 0; j < 4; ++j)
                    acc[i][j] = __builtin_amdgcn_mfma_f32_16x16x32_bf16(af[i], bfr[j], acc[i][j], 0, 0, 0);
        }
    }
}

// Fused QKV projection. grid = (32, 24). Q pre-scaled by log2(e)/8.
// Q,K stored [B,H,S,64] via LDS-transpose float4 stores; V stored transposed [B,H,64,S].
__global__ __launch_bounds__(256, 3) void qkv_kernel(
    const ushort_t* __restrict__ x,
    const ushort_t* __restrict__ Wq, const ushort_t* __restrict__ bq,
    const ushort_t* __restrict__ Wk, const ushort_t* __restrict__ bk,
    const ushort_t* __restrict__ Wv, const ushort_t* __restrict__ bv,
    ushort_t* __restrict__ q_ws, ushort_t* __restrict__ k_ws, ushort_t* __restrict__ vt_ws)
{
    __shared__ __align__(16) ushort_t lds[17408];  // max(4*128*32, 128*136)
    const int m0 = blockIdx.x * 128;
    const int which = blockIdx.y >> 3;
    const int n0 = (blockIdx.y & 7) * 128;
    const ushort_t* W    = (which == 0) ? Wq : (which == 1) ? Wk : Wv;
    const ushort_t* bias = (which == 0) ? bq : (which == 1) ? bk : bv;
    floatx4 acc[4][4];
    gemm_core(x, W, m0, n0, lds, acc);
    const int tid = threadIdx.x, lane = tid & 63, wv = tid >> 6;
    const int wm = (wv >> 1) * 64, wn = (wv & 1) * 64;
    const int l15 = lane & 15, quad = lane >> 4;
    const int b0 = m0 >> 11;
    const int s0 = m0 & (SEQ - 1);
    __syncthreads();  // all waves done reading staging tiles before reuse as Ts
    if (which < 2) {
        // C -> Ts [128 m][136 n], then coalesced float4 stores to [B,H,S,64]
        ushort_t* Ts = lds;
        ushort_t* dst = (which == 0) ? q_ws : k_ws;
        const float scl = (which == 0) ? QSCALE : 1.0f;
#pragma unroll
        for (int j = 0; j < 4; ++j) {
            int coln = wn + j * 16 + l15;
            float bb = bf2f(bias[n0 + coln]);
#pragma unroll
            for (int i = 0; i < 4; ++i)
#pragma unroll
                for (int r = 0; r < 4; ++r) {
                    int rowm = wm + i * 16 + quad * 4 + r;
                    Ts[rowm * 136 + coln] = f2bf((acc[i][j][r] + bb) * scl);
                }
        }
        __syncthreads();
#pragma unroll
        for (int i = 0; i < 8; ++i) {
            int c = tid + 256 * i;  // 128 rows x 16 chunks
            int rowm = c >> 4, chunk = c & 15;
            float4 v = *reinterpret_cast<const float4*>(Ts + rowm * 136 + chunk * 8);
            int s = s0 + rowm;
            int n = n0 + chunk * 8, h = n >> 6, d = n & 63;
            *reinterpret_cast<float4*>(dst + (((size_t)(b0 * NH + h)) * SEQ + s) * DKH + d) = v;
        }
    } else {
        ushort_t* Ts = lds;  // [128 n][136 m]
#pragma unroll
        for (int j = 0; j < 4; ++j) {
            int coln = wn + j * 16 + l15;
            float bb = bf2f(bias[n0 + coln]);
#pragma unroll
            for (int i = 0; i < 4; ++i)
#pragma unroll
                for (int r = 0; r < 4; ++r) {
                    int rowm = wm + i * 16 + quad * 4 + r;
                    Ts[coln * 136 + rowm] = f2bf(acc[i][j][r] + bb);
                }
        }
        __syncthreads();
#pragma unroll
        for (int i = 0; i < 8; ++i) {
            int c = tid + 256 * i;
            int nr = c >> 4, mc = (c & 15) * 8;
            float4 v = *reinterpret_cast<const float4*>(Ts + nr * 136 + mc);
            int n = n0 + nr, h = n >> 6, d = n & 63;
            *reinterpret_cast<float4*>(vt_ws + (((size_t)(b0 * NH + h)) * DKH + d) * SEQ + s0 + mc) = v;
        }
    }
}

// Flash attention, S^T formulation, no-max softmax, REGISTER-RESIDENT P.
// grid = (32 q-tiles, 32 b*h), 256 threads = 4 waves: waves 0-1 KV rows
// 0..1023, waves 2-3 rows 1024..2047; each wave owns 32 q-rows.
// QK^T: S^T = K·Q^T (x32 MFMA). PV: O^T = V^T·P^T via x16 MFMA whose
// B-fragment layout (k=quad*4+r, col=l15) IS S^T's C-layout -> P never
// touches LDS. Halves merge linearly (no-max softmax) through LDS at the end.
__global__ __launch_bounds__(256, 4) void attn_kernel(
    const ushort_t* __restrict__ q_ws, const ushort_t* __restrict__ k_ws,
    const ushort_t* __restrict__ vt_ws, ushort_t* __restrict__ concat)
{
    __shared__ __align__(16) ushort_t sm[18432];  // 36.9 KB -> 4 blocks/CU
    // [0,9216): K staging [half][64][72]; [9216,18432): V^T staging [half][64][72]
    const int qb = blockIdx.x, bh = blockIdx.y;
    const int tid = threadIdx.x;
    const int lane = tid & 63, wv = tid >> 6;
    const int half = wv >> 1, wq = wv & 1;
    const int l15 = lane & 15, quad = lane >> 4;
    const int ht = tid & 127;  // thread id within half-group

    const ushort_t* Qg = q_ws + ((size_t)bh * SEQ + qb * 64) * DKH;
    const ushort_t* Kg = k_ws + ((size_t)bh * SEQ + half * (SEQ / 2)) * DKH;
    const ushort_t* Vg = vt_ws + (size_t)bh * DKH * SEQ + half * (SEQ / 2);

    ushort_t* Ks  = sm + half * 4608;
    ushort_t* VTs = sm + 9216 + half * 4608;

    // Q fragments straight from global (one-time, no LDS)
    bf16x8 aq[2][2];
#pragma unroll
    for (int nt = 0; nt < 2; ++nt)
#pragma unroll
        for (int ks = 0; ks < 2; ++ks)
            aq[nt][ks] = *reinterpret_cast<const bf16x8*>(
                Qg + (size_t)(wq * 32 + nt * 16 + l15) * DKH + ks * 32 + quad * 8);

    const floatx4 z4 = {0.f, 0.f, 0.f, 0.f};
    floatx4 o[2][4];       // O^T: C-layout d=dt*16+quad*4+r, q=l15 (per nt)
    floatx4 la4[2] = {z4, z4};
#pragma unroll
    for (int nt = 0; nt < 2; ++nt)
#pragma unroll
        for (int dt = 0; dt < 4; ++dt) o[nt][dt] = z4;

    for (int t = 0; t < 16; ++t) {
        __syncthreads();  // prior tile's MFMA reads of Ks/VTs done
#pragma unroll
        for (int i = 0; i < 4; ++i) {
            int c = ht + 128 * i;  // 0..511
            int row = c >> 3, col = (c & 7) * 8;
            *reinterpret_cast<float4*>(Ks + row * 72 + col) =
                *reinterpret_cast<const float4*>(Kg + (size_t)(t * 64 + row) * DKH + col);
            *reinterpret_cast<float4*>(VTs + row * 72 + col) =
                *reinterpret_cast<const float4*>(Vg + (size_t)row * SEQ + t * 64 + col);
        }
        __syncthreads();

        // S^T = K·Q^T : 64 kcols x 32 qrows per wave
        floatx4 st[2][4];
#pragma unroll
        for (int nt = 0; nt < 2; ++nt)
#pragma unroll
            for (int mt = 0; mt < 4; ++mt) st[nt][mt] = z4;
#pragma unroll
        for (int ks = 0; ks < 2; ++ks)
#pragma unroll
            for (int mt = 0; mt < 4; ++mt) {
                bf16x8 akf = *reinterpret_cast<const bf16x8*>(Ks + (mt * 16 + l15) * 72 + ks * 32 + quad * 8);
                st[0][mt] = __builtin_amdgcn_mfma_f32_16x16x32_bf16(akf, aq[0][ks], st[0][mt], 0, 0, 0);
                st[1][mt] = __builtin_amdgcn_mfma_f32_16x16x32_bf16(akf, aq[1][ks], st[1][mt], 0, 0, 0);
            }

        // p = 2^s (log2 domain), vector l-accumulate, pack to x16 B-fragments
        short4v pb[2][4];
#pragma unroll
        for (int nt = 0; nt < 2; ++nt)
#pragma unroll
            for (int mt = 0; mt < 4; ++mt) {
#pragma unroll
                for (int r = 0; r < 4; ++r) st[nt][mt][r] = exp2f(st[nt][mt][r]);
                la4[nt] += st[nt][mt];
                pb[nt][mt] = pack4bf(st[nt][mt]);
            }

        // O^T += V^T · P^T  (x16 MFMA, P from registers)
#pragma unroll
        for (int mt = 0; mt < 4; ++mt)
#pragma unroll
            for (int dt = 0; dt < 4; ++dt) {
                short4v av = *reinterpret_cast<const short4v*>(VTs + (dt * 16 + l15) * 72 + mt * 16 + quad * 4);
                o[0][dt] = MFMA16(av, pb[0][mt], o[0][dt]);
                o[1][dt] = MFMA16(av, pb[1][mt], o[1][dt]);
            }
    }
    // per-q row sums: lane l15 of each quad holds q = wq*32+nt*16+l15
    float lsum[2];
#pragma unroll
    for (int nt = 0; nt < 2; ++nt) {
        float s = la4[nt][0] + la4[nt][1] + la4[nt][2] + la4[nt][3];
        s += __shfl_xor(s, 16, 64);
        s += __shfl_xor(s, 32, 64);
        lsum[nt] = s;
    }
    // merge halves (linear): O = O0+O1, l = l0+l1, through LDS
    __syncthreads();
    float* Of = (float*)sm;        // [64 d][65]
    float* lf = Of + 64 * 65;      // [64 q]
    if (half == 1) {
#pragma unroll
        for (int nt = 0; nt < 2; ++nt) {
            int q = wq * 32 + nt * 16 + l15;
            if (quad == 0) lf[q] = lsum[nt];
#pragma unroll
            for (int dt = 0; dt < 4; ++dt)
#pragma unroll
                for (int r = 0; r < 4; ++r)
                    Of[(dt * 16 + quad * 4 + r) * 65 + q] = o[nt][dt][r];
        }
    }
    __syncthreads();
    if (half == 0) {
        const int b0 = bh >> 4, h = bh & 15;
#pragma unroll
        for (int nt = 0; nt < 2; ++nt) {
            int q = wq * 32 + nt * 16 + l15;
            float linv = 1.f / (lsum[nt] + lf[q]);
            size_t base = ((size_t)(b0 * SEQ + qb * 64 + q)) * D_MODEL + h * DKH;
#pragma unroll
            for (int dt = 0; dt < 4; ++dt) {
                float f0 = (o[nt][dt][0] + Of[(dt * 16 + quad * 4 + 0) * 65 + q]) * linv;
                float f1 = (o[nt][dt][1] + Of[(dt * 16 + quad * 4 + 1) * 65 + q]) * linv;
                float f2 = (o[nt][dt][2] + Of[(dt * 16 + quad * 4 + 2) * 65 + q]) * linv;
                float f3 = (o[nt][dt][3] + Of[(dt * 16 + quad * 4 + 3) * 65 + q]) * linv;
                uint2 pk;
                pk.x = pack2bf(f0, f1);
                pk.y = pack2bf(f2, f3);
                *reinterpret_cast<uint2*>(concat + base + dt * 16 + quad * 4) = pk;
            }
        }
    }
}

// Output projection: out = concat @ Wo^T + bo. grid = (32, 8). fp32 output.
__global__ __launch_bounds__(256, 3) void oproj_kernel(
    const ushort_t* __restrict__ cc, const ushort_t* __restrict__ Wo,
    const ushort_t* __restrict__ bo, float* __restrict__ out)
{
    __shared__ __align__(16) ushort_t lds[4 * 128 * 32];
    const int m0 = blockIdx.x * 128, n0 = blockIdx.y * 128;
    floatx4 acc[4][4];
    gemm_core(cc, Wo, m0, n0, lds, acc);
    const int tid = threadIdx.x, lane = tid & 63, wv = tid >> 6;
    const int wm = (wv >> 1) * 64, wn = (wv & 1) * 64;
    const int l15 = lane & 15, quad = lane >> 4;
#pragma unroll
    for (int j = 0; j < 4; ++j) {
        int n = n0 + wn + j * 16 + l15;
        float bb = bf2f(bo[n]);
#pragma unroll
        for (int i = 0; i < 4; ++i)
#pragma unroll
            for (int r = 0; r < 4; ++r) {
                int m = m0 + wm + i * 16 + quad * 4 + r;
                out[(size_t)m * D_MODEL + n] = acc[i][j][r] + bb;
            }
    }
}

extern "C" void kernel_launch(void* const* d_in, const int* in_sizes, int n_in,
                              void* d_out, int out_size, void* d_ws, size_t ws_size,
                              hipStream_t stream)
{
    ushort_t* cvt = (ushort_t*)d_ws;
    const ushort_t* xb  = cvt + OFF_X;
    const ushort_t* Wqb = cvt + OFF_WQ;
    const ushort_t* bqb = cvt + OFF_BQ;
    const ushort_t* Wkb = cvt + OFF_WK;
    const ushort_t* bkb = cvt + OFF_BK;
    const ushort_t* Wvb = cvt + OFF_WV;
    const ushort_t* bvb = cvt + OFF_BV;
    const ushort_t* Wob = cvt + OFF_WO;
    const ushort_t* bob = cvt + OFF_BO;
    ushort_t* q_ws   = cvt + CVT_TOT;                        // [B,H,S,64] (Q pre-scaled)
    ushort_t* k_ws   = q_ws  + (size_t)MTOT * D_MODEL;       // [B,H,S,64]
    ushort_t* vt_ws  = k_ws  + (size_t)MTOT * D_MODEL;       // [B,H,64,S]
    ushort_t* concat = vt_ws + (size_t)MTOT * D_MODEL;       // [B,S,D]

    convert_kernel<<<(CVT_TOT / 1024), 256, 0, stream>>>(
        (const float*)d_in[0], (const float*)d_in[1], (const float*)d_in[2],
        (const float*)d_in[3], (const float*)d_in[4], (const float*)d_in[5],
        (const float*)d_in[6], (const float*)d_in[7], (const float*)d_in[8], cvt);
    qkv_kernel<<<dim3(32, 24), 256, 0, stream>>>(xb, Wqb, bqb, Wkb, bkb, Wvb, bvb, q_ws, k_ws, vt_ws);
    attn_kernel<<<dim3(32, 32), 256, 0, stream>>>(q_ws, k_ws, vt_ws, concat);
    oproj_kernel<<<dim3(32, 8), 256, 0, stream>>>(concat, Wob, bob, (float*)d_out);
}

// Round 10
// 210.390 us; speedup vs baseline: 1.0758x; 1.0758x over previous
//
#include <hip/hip_runtime.h>

typedef unsigned short ushort_t;
typedef __attribute__((ext_vector_type(8))) __bf16 bf16x8;
typedef __attribute__((ext_vector_type(4))) short short4v;
typedef __attribute__((ext_vector_type(4))) float floatx4;

#define AS1 __attribute__((address_space(1)))
#define AS3 __attribute__((address_space(3)))

#define D_MODEL 1024
#define NH 16
#define DKH 64
#define SEQ 2048
#define NB 2
#define MTOT (NB * SEQ)

// log2(e) / sqrt(dk) folded into Q at projection time
#define QSCALE 0.18033688011112042f

// converted-region segment offsets (elements), input order x,Wq,bq,Wk,bk,Wv,bv,Wo,bo
#define OFF_X   0u
#define OFF_WQ  4194304u
#define OFF_BQ  5242880u
#define OFF_WK  5243904u
#define OFF_BK  6292480u
#define OFF_WV  6293504u
#define OFF_BV  7342080u
#define OFF_WO  7343104u
#define OFF_BO  8391680u
#define CVT_TOT 8392704u

// K=16 MFMA: P^T exits QK^T's C-layout exactly in this op's B-fragment layout
// (lane holds k=quad*4+r, col=l15) -> PV needs no LDS round-trip.
// NOTE: never gate device builtins on __has_builtin (false in HIP host pass).
#define MFMA16(a, b, c) __builtin_amdgcn_mfma_f32_16x16x16bf16_1k((a), (b), (c), 0, 0, 0)

__device__ __forceinline__ float bf2f(ushort_t u) {
    union { unsigned u; float f; } v; v.u = ((unsigned)u) << 16; return v.f;
}
__device__ __forceinline__ ushort_t f2bf(float f) {
    union { float f; unsigned u; } v; v.f = f;
    unsigned r = v.u + 0x7FFFu + ((v.u >> 16) & 1u);  // RNE
    return (ushort_t)(r >> 16);
}
// pack two fp32 -> two bf16 (RNE): low half = bf(a), high = bf(b)
__device__ __forceinline__ unsigned pack2bf(float a, float b) {
    unsigned ua = __float_as_uint(a), ub = __float_as_uint(b);
    ua = ua + 0x7FFFu + ((ua >> 16) & 1u);
    ub = ub + 0x7FFFu + ((ub >> 16) & 1u);
    return __builtin_amdgcn_perm(ub, ua, 0x07060302);
}
__device__ __forceinline__ short4v pack4bf(floatx4 v) {
    union { uint2 u; short4v s; } cv;
    cv.u.x = pack2bf(v[0], v[1]);
    cv.u.y = pack2bf(v[2], v[3]);
    return cv.s;
}

// ---------- convert all fp32 inputs into one contiguous bf16 region ----------
// R9 BUG (fixed): the wv branch had `off = idx - OFF_BV` (unsigned wrap -> OOB
// read -> device abort). Every branch must subtract its own segment base.
__global__ __launch_bounds__(256) void convert_kernel(
    const float* __restrict__ x,  const float* __restrict__ wq, const float* __restrict__ bq_,
    const float* __restrict__ wk, const float* __restrict__ bk_, const float* __restrict__ wv,
    const float* __restrict__ bv_, const float* __restrict__ wo, const float* __restrict__ bo_,
    ushort_t* __restrict__ dst)
{
    const unsigned idx = ((unsigned)blockIdx.x * 256u + threadIdx.x) * 4u;
    if (idx >= CVT_TOT) return;
    const float* src; unsigned off;
    if      (idx < OFF_WQ) { src = x;   off = idx - OFF_X;  }
    else if (idx < OFF_BQ) { src = wq;  off = idx - OFF_WQ; }
    else if (idx < OFF_WK) { src = bq_; off = idx - OFF_BQ; }
    else if (idx < OFF_BK) { src = wk;  off = idx - OFF_WK; }
    else if (idx < OFF_WV) { src = bk_; off = idx - OFF_BK; }
    else if (idx < OFF_BV) { src = wv;  off = idx - OFF_WV; }
    else if (idx < OFF_WO) { src = bv_; off = idx - OFF_BV; }
    else if (idx < OFF_BO) { src = wo;  off = idx - OFF_WO; }
    else                   { src = bo_; off = idx - OFF_BO; }
    float4 v = *reinterpret_cast<const float4*>(src + off);
    uint2 p;
    p.x = pack2bf(v.x, v.y);
    p.y = pack2bf(v.z, v.w);
    *reinterpret_cast<uint2*>(dst + idx) = p;
}

// GEMM core, BK=64 via two unpadded [128][32] sub-tiles (m97 bank pattern,
// global_load_lds width-16). 32 MFMA per barrier pair, 16 iters at K=1024.
__device__ __forceinline__ void gemm_core(
    const ushort_t* __restrict__ X, const ushort_t* __restrict__ W,
    int m0, int n0, ushort_t* lds, floatx4 acc[4][4])
{
    const int tid = threadIdx.x;
    const int lane = tid & 63, wv = tid >> 6;
    const int wm = (wv >> 1) * 64, wn = (wv & 1) * 64;
    const int l15 = lane & 15, quad = lane >> 4;
    const floatx4 z4 = {0.f, 0.f, 0.f, 0.f};
#pragma unroll
    for (int i = 0; i < 4; ++i)
#pragma unroll
        for (int j = 0; j < 4; ++j) acc[i][j] = z4;
    const int lrow = lane >> 2;
    const int lcol = (lane & 3) * 8;
    const ushort_t* gA = X + (size_t)(m0 + lrow) * D_MODEL + lcol;
    const ushort_t* gB = W + (size_t)(n0 + lrow) * D_MODEL + lcol;
    for (int k0 = 0; k0 < D_MODEL; k0 += 64) {
        __syncthreads();
#pragma unroll
        for (int j = 0; j < 2; ++j) {
            const int r0 = (wv * 2 + j) * 16;
            __builtin_amdgcn_global_load_lds(
                (const AS1 unsigned*)(gA + (size_t)r0 * D_MODEL + k0),
                (AS3 unsigned*)(lds + r0 * 32), 16, 0, 0);
            __builtin_amdgcn_global_load_lds(
                (const AS1 unsigned*)(gA + (size_t)r0 * D_MODEL + k0 + 32),
                (AS3 unsigned*)(lds + 4096 + r0 * 32), 16, 0, 0);
            __builtin_amdgcn_global_load_lds(
                (const AS1 unsigned*)(gB + (size_t)r0 * D_MODEL + k0),
                (AS3 unsigned*)(lds + 8192 + r0 * 32), 16, 0, 0);
            __builtin_amdgcn_global_load_lds(
                (const AS1 unsigned*)(gB + (size_t)r0 * D_MODEL + k0 + 32),
                (AS3 unsigned*)(lds + 12288 + r0 * 32), 16, 0, 0);
        }
        asm volatile("s_waitcnt vmcnt(0)" ::: "memory");
        __syncthreads();
#pragma unroll
        for (int ks = 0; ks < 2; ++ks) {
            const ushort_t* A = lds + ks * 4096;
            const ushort_t* B = lds + 8192 + ks * 4096;
            bf16x8 af[4], bfr[4];
#pragma unroll
            for (int i = 0; i < 4; ++i)
                af[i] = *reinterpret_cast<const bf16x8*>(A + (wm + i * 16 + l15) * 32 + quad * 8);
#pragma unroll
            for (int j = 0; j < 4; ++j)
                bfr[j] = *reinterpret_cast<const bf16x8*>(B + (wn + j * 16 + l15) * 32 + quad * 8);
#pragma unroll
            for (int i = 0; i < 4; ++i)
#pragma unroll
                for (int j = 0; j < 4; ++j)
                    acc[i][j] = __builtin_amdgcn_mfma_f32_16x16x32_bf16(af[i], bfr[j], acc[i][j], 0, 0, 0);
        }
    }
}

// Fused QKV projection. grid = (32, 24). Q pre-scaled by log2(e)/8.
__global__ __launch_bounds__(256, 3) void qkv_kernel(
    const ushort_t* __restrict__ x,
    const ushort_t* __restrict__ Wq, const ushort_t* __restrict__ bq,
    const ushort_t* __restrict__ Wk, const ushort_t* __restrict__ bk,
    const ushort_t* __restrict__ Wv, const ushort_t* __restrict__ bv,
    ushort_t* __restrict__ q_ws, ushort_t* __restrict__ k_ws, ushort_t* __restrict__ vt_ws)
{
    __shared__ __align__(16) ushort_t lds[17408];
    const int m0 = blockIdx.x * 128;
    const int which = blockIdx.y >> 3;
    const int n0 = (blockIdx.y & 7) * 128;
    const ushort_t* W    = (which == 0) ? Wq : (which == 1) ? Wk : Wv;
    const ushort_t* bias = (which == 0) ? bq : (which == 1) ? bk : bv;
    floatx4 acc[4][4];
    gemm_core(x, W, m0, n0, lds, acc);
    const int tid = threadIdx.x, lane = tid & 63, wv = tid >> 6;
    const int wm = (wv >> 1) * 64, wn = (wv & 1) * 64;
    const int l15 = lane & 15, quad = lane >> 4;
    const int b0 = m0 >> 11;
    const int s0 = m0 & (SEQ - 1);
    __syncthreads();
    if (which < 2) {
        ushort_t* Ts = lds;  // [128 m][136 n]
        ushort_t* dst = (which == 0) ? q_ws : k_ws;
        const float scl = (which == 0) ? QSCALE : 1.0f;
#pragma unroll
        for (int j = 0; j < 4; ++j) {
            int coln = wn + j * 16 + l15;
            float bb = bf2f(bias[n0 + coln]);
#pragma unroll
            for (int i = 0; i < 4; ++i)
#pragma unroll
                for (int r = 0; r < 4; ++r) {
                    int rowm = wm + i * 16 + quad * 4 + r;
                    Ts[rowm * 136 + coln] = f2bf((acc[i][j][r] + bb) * scl);
                }
        }
        __syncthreads();
#pragma unroll
        for (int i = 0; i < 8; ++i) {
            int c = tid + 256 * i;
            int rowm = c >> 4, chunk = c & 15;
            float4 v = *reinterpret_cast<const float4*>(Ts + rowm * 136 + chunk * 8);
            int s = s0 + rowm;
            int n = n0 + chunk * 8, h = n >> 6, d = n & 63;
            *reinterpret_cast<float4*>(dst + (((size_t)(b0 * NH + h)) * SEQ + s) * DKH + d) = v;
        }
    } else {
        ushort_t* Ts = lds;  // [128 n][136 m]
#pragma unroll
        for (int j = 0; j < 4; ++j) {
            int coln = wn + j * 16 + l15;
            float bb = bf2f(bias[n0 + coln]);
#pragma unroll
            for (int i = 0; i < 4; ++i)
#pragma unroll
                for (int r = 0; r < 4; ++r) {
                    int rowm = wm + i * 16 + quad * 4 + r;
                    Ts[coln * 136 + rowm] = f2bf(acc[i][j][r] + bb);
                }
        }
        __syncthreads();
#pragma unroll
        for (int i = 0; i < 8; ++i) {
            int c = tid + 256 * i;
            int nr = c >> 4, mc = (c & 15) * 8;
            float4 v = *reinterpret_cast<const float4*>(Ts + nr * 136 + mc);
            int n = n0 + nr, h = n >> 6, d = n & 63;
            *reinterpret_cast<float4*>(vt_ws + (((size_t)(b0 * NH + h)) * DKH + d) * SEQ + s0 + mc) = v;
        }
    }
}

// Flash attention: BQ=128, 512 threads (8 waves), 2-half KV split in-block,
// register-resident P (x16 PV MFMA), software-pipelined KV staging (prefetch
// tile t+1 into VGPRs before compute(t) so global latency retires under MFMA).
// grid = (16 q-tiles, 32 b*h). Each wave owns 32 q-rows over its half of KV.
__global__ __launch_bounds__(512, 4) void attn_kernel(
    const ushort_t* __restrict__ q_ws, const ushort_t* __restrict__ k_ws,
    const ushort_t* __restrict__ vt_ws, ushort_t* __restrict__ concat)
{
    __shared__ __align__(16) ushort_t sm[18432];  // 36.9 KB
    // [0,9216): K staging [half][64][72]; [9216,18432): V^T staging [half][64][72]
    const int qb = blockIdx.x, bh = blockIdx.y;
    const int tid = threadIdx.x;
    const int lane = tid & 63, wv = tid >> 6;
    const int half = wv >> 2, wq = wv & 3;
    const int l15 = lane & 15, quad = lane >> 4;
    const int ht = tid & 255;  // thread id within half-group

    const ushort_t* Qg = q_ws + ((size_t)bh * SEQ + qb * 128) * DKH;
    const ushort_t* Kg = k_ws + ((size_t)bh * SEQ + half * (SEQ / 2)) * DKH;
    const ushort_t* Vg = vt_ws + (size_t)bh * DKH * SEQ + half * (SEQ / 2);

    ushort_t* Ks  = sm + half * 4608;
    ushort_t* VTs = sm + 9216 + half * 4608;

    // staging geometry: 512 chunks of 8 elts cover [64][64]; this thread owns 2
    const int r0c = ht >> 3,         c0c = (ht & 7) * 8;
    const int r1c = (ht + 256) >> 3, c1c = ((ht + 256) & 7) * 8;

    // Q fragments straight from global (one-time)
    bf16x8 aq[2][2];
#pragma unroll
    for (int nt = 0; nt < 2; ++nt)
#pragma unroll
        for (int ks = 0; ks < 2; ++ks)
            aq[nt][ks] = *reinterpret_cast<const bf16x8*>(
                Qg + (size_t)(wq * 32 + nt * 16 + l15) * DKH + ks * 32 + quad * 8);

    const floatx4 z4 = {0.f, 0.f, 0.f, 0.f};
    floatx4 o[2][4];       // O^T: d = dt*16+quad*4+r, q = l15 (per nt)
    floatx4 la4[2] = {z4, z4};
#pragma unroll
    for (int nt = 0; nt < 2; ++nt)
#pragma unroll
        for (int dt = 0; dt < 4; ++dt) o[nt][dt] = z4;

    // prologue: prefetch tile 0
    float4 pk0 = *reinterpret_cast<const float4*>(Kg + (size_t)r0c * DKH + c0c);
    float4 pk1 = *reinterpret_cast<const float4*>(Kg + (size_t)r1c * DKH + c1c);
    float4 pv0 = *reinterpret_cast<const float4*>(Vg + (size_t)r0c * SEQ + c0c);
    float4 pv1 = *reinterpret_cast<const float4*>(Vg + (size_t)r1c * SEQ + c1c);

    for (int t = 0; t < 16; ++t) {
        __syncthreads();  // prior tile's MFMA reads of Ks/VTs done
        *reinterpret_cast<float4*>(Ks + r0c * 72 + c0c) = pk0;
        *reinterpret_cast<float4*>(Ks + r1c * 72 + c1c) = pk1;
        *reinterpret_cast<float4*>(VTs + r0c * 72 + c0c) = pv0;
        *reinterpret_cast<float4*>(VTs + r1c * 72 + c1c) = pv1;
        __syncthreads();
        if (t < 15) {  // prefetch next tile; retires during compute below
            int toff = (t + 1) * 64;
            pk0 = *reinterpret_cast<const float4*>(Kg + (size_t)(toff + r0c) * DKH + c0c);
            pk1 = *reinterpret_cast<const float4*>(Kg + (size_t)(toff + r1c) * DKH + c1c);
            pv0 = *reinterpret_cast<const float4*>(Vg + (size_t)r0c * SEQ + toff + c0c);
            pv1 = *reinterpret_cast<const float4*>(Vg + (size_t)r1c * SEQ + toff + c1c);
        }

        // S^T = K·Q^T : 64 kcols x 32 qrows per wave
        floatx4 st[2][4];
#pragma unroll
        for (int nt = 0; nt < 2; ++nt)
#pragma unroll
            for (int mt = 0; mt < 4; ++mt) st[nt][mt] = z4;
#pragma unroll
        for (int ks = 0; ks < 2; ++ks)
#pragma unroll
            for (int mt = 0; mt < 4; ++mt) {
                bf16x8 akf = *reinterpret_cast<const bf16x8*>(Ks + (mt * 16 + l15) * 72 + ks * 32 + quad * 8);
                st[0][mt] = __builtin_amdgcn_mfma_f32_16x16x32_bf16(akf, aq[0][ks], st[0][mt], 0, 0, 0);
                st[1][mt] = __builtin_amdgcn_mfma_f32_16x16x32_bf16(akf, aq[1][ks], st[1][mt], 0, 0, 0);
            }

        // p = 2^s (log2 domain), vector l-accumulate, pack to x16 B-fragments
        short4v pb[2][4];
#pragma unroll
        for (int nt = 0; nt < 2; ++nt)
#pragma unroll
            for (int mt = 0; mt < 4; ++mt) {
#pragma unroll
                for (int r = 0; r < 4; ++r) st[nt][mt][r] = exp2f(st[nt][mt][r]);
                la4[nt] += st[nt][mt];
                pb[nt][mt] = pack4bf(st[nt][mt]);
            }

        // O^T += V^T · P^T  (x16 MFMA, P from registers)
#pragma unroll
        for (int mt = 0; mt < 4; ++mt)
#pragma unroll
            for (int dt = 0; dt < 4; ++dt) {
                short4v av = *reinterpret_cast<const short4v*>(VTs + (dt * 16 + l15) * 72 + mt * 16 + quad * 4);
                o[0][dt] = MFMA16(av, pb[0][mt], o[0][dt]);
                o[1][dt] = MFMA16(av, pb[1][mt], o[1][dt]);
            }
    }
    // per-q row sums (q = wq*32+nt*16+l15; quads hold copies)
    float lsum[2];
#pragma unroll
    for (int nt = 0; nt < 2; ++nt) {
        float s = la4[nt][0] + la4[nt][1] + la4[nt][2] + la4[nt][3];
        s += __shfl_xor(s, 16, 64);
        s += __shfl_xor(s, 32, 64);
        lsum[nt] = s;
    }
    // merge halves (linear, no-max softmax): O = O0+O1, l = l0+l1
    __syncthreads();
    float* Of = (float*)sm;        // [64 d][130 q]  (33280 B)
    float* lf = Of + 64 * 130;     // [128 q]        (+512 B = 33.8 KB <= 36.9 KB)
    if (half == 1) {
#pragma unroll
        for (int nt = 0; nt < 2; ++nt) {
            int q = wq * 32 + nt * 16 + l15;
            if (quad == 0) lf[q] = lsum[nt];
#pragma unroll
            for (int dt = 0; dt < 4; ++dt)
#pragma unroll
                for (int r = 0; r < 4; ++r)
                    Of[(dt * 16 + quad * 4 + r) * 130 + q] = o[nt][dt][r];
        }
    }
    __syncthreads();
    if (half == 0) {
        const int b0 = bh >> 4, h = bh & 15;
#pragma unroll
        for (int nt = 0; nt < 2; ++nt) {
            int q = wq * 32 + nt * 16 + l15;
            float linv = 1.f / (lsum[nt] + lf[q]);
            size_t base = ((size_t)(b0 * SEQ + qb * 128 + q)) * D_MODEL + h * DKH;
#pragma unroll
            for (int dt = 0; dt < 4; ++dt) {
                float f0 = (o[nt][dt][0] + Of[(dt * 16 + quad * 4 + 0) * 130 + q]) * linv;
                float f1 = (o[nt][dt][1] + Of[(dt * 16 + quad * 4 + 1) * 130 + q]) * linv;
                float f2 = (o[nt][dt][2] + Of[(dt * 16 + quad * 4 + 2) * 130 + q]) * linv;
                float f3 = (o[nt][dt][3] + Of[(dt * 16 + quad * 4 + 3) * 130 + q]) * linv;
                uint2 pk;
                pk.x = pack2bf(f0, f1);
                pk.y = pack2bf(f2, f3);
                *reinterpret_cast<uint2*>(concat + base + dt * 16 + quad * 4) = pk;
            }
        }
    }
}

// Output projection: out = concat @ Wo^T + bo. grid = (32, 8). fp32 output.
__global__ __launch_bounds__(256, 3) void oproj_kernel(
    const ushort_t* __restrict__ cc, const ushort_t* __restrict__ Wo,
    const ushort_t* __restrict__ bo, float* __restrict__ out)
{
    __shared__ __align__(16) ushort_t lds[4 * 128 * 32];
    const int m0 = blockIdx.x * 128, n0 = blockIdx.y * 128;
    floatx4 acc[4][4];
    gemm_core(cc, Wo, m0, n0, lds, acc);
    const int tid = threadIdx.x, lane = tid & 63, wv = tid >> 6;
    const int wm = (wv >> 1) * 64, wn = (wv & 1) * 64;
    const int l15 = lane & 15, quad = lane >> 4;
#pragma unroll
    for (int j = 0; j < 4; ++j) {
        int n = n0 + wn + j * 16 + l15;
        float bb = bf2f(bo[n]);
#pragma unroll
        for (int i = 0; i < 4; ++i)
#pragma unroll
            for (int r = 0; r < 4; ++r) {
                int m = m0 + wm + i * 16 + quad * 4 + r;
                out[(size_t)m * D_MODEL + n] = acc[i][j][r] + bb;
            }
    }
}

extern "C" void kernel_launch(void* const* d_in, const int* in_sizes, int n_in,
                              void* d_out, int out_size, void* d_ws, size_t ws_size,
                              hipStream_t stream)
{
    ushort_t* cvt = (ushort_t*)d_ws;
    const ushort_t* xb  = cvt + OFF_X;
    const ushort_t* Wqb = cvt + OFF_WQ;
    const ushort_t* bqb = cvt + OFF_BQ;
    const ushort_t* Wkb = cvt + OFF_WK;
    const ushort_t* bkb = cvt + OFF_BK;
    const ushort_t* Wvb = cvt + OFF_WV;
    const ushort_t* bvb = cvt + OFF_BV;
    const ushort_t* Wob = cvt + OFF_WO;
    const ushort_t* bob = cvt + OFF_BO;
    ushort_t* q_ws   = cvt + CVT_TOT;                        // [B,H,S,64] (Q pre-scaled)
    ushort_t* k_ws   = q_ws  + (size_t)MTOT * D_MODEL;       // [B,H,S,64]
    ushort_t* vt_ws  = k_ws  + (size_t)MTOT * D_MODEL;       // [B,H,64,S]
    ushort_t* concat = vt_ws + (size_t)MTOT * D_MODEL;       // [B,S,D]

    convert_kernel<<<(CVT_TOT / 1024), 256, 0, stream>>>(
        (const float*)d_in[0], (const float*)d_in[1], (const float*)d_in[2],
        (const float*)d_in[3], (const float*)d_in[4], (const float*)d_in[5],
        (const float*)d_in[6], (const float*)d_in[7], (const float*)d_in[8], cvt);
    qkv_kernel<<<dim3(32, 24), 256, 0, stream>>>(xb, Wqb, bqb, Wkb, bkb, Wvb, bvb, q_ws, k_ws, vt_ws);
    attn_kernel<<<dim3(16, 32), 512, 0, stream>>>(q_ws, k_ws, vt_ws, concat);
    oproj_kernel<<<dim3(32, 8), 256, 0, stream>>>(concat, Wob, bob, (float*)d_out);
}

// Round 11
// 210.044 us; speedup vs baseline: 1.0776x; 1.0016x over previous
//
#include <hip/hip_runtime.h>

typedef unsigned short ushort_t;
typedef __attribute__((ext_vector_type(8))) __bf16 bf16x8;
typedef __attribute__((ext_vector_type(4))) float floatx4;

#define AS1 __attribute__((address_space(1)))
#define AS3 __attribute__((address_space(3)))

#define D_MODEL 1024
#define NH 16
#define DKH 64
#define SEQ 2048
#define NB 2
#define MTOT (NB * SEQ)

// log2(e) / sqrt(dk) folded into Q at projection time
#define QSCALE 0.18033688011112042f

// converted-region segment offsets (elements), input order x,Wq,bq,Wk,bk,Wv,bv,Wo,bo
#define OFF_X   0u
#define OFF_WQ  4194304u
#define OFF_BQ  5242880u
#define OFF_WK  5243904u
#define OFF_BK  6292480u
#define OFF_WV  6293504u
#define OFF_BV  7342080u
#define OFF_WO  7343104u
#define OFF_BO  8391680u
#define CVT_TOT 8392704u

__device__ __forceinline__ float bf2f(ushort_t u) {
    union { unsigned u; float f; } v; v.u = ((unsigned)u) << 16; return v.f;
}
__device__ __forceinline__ ushort_t f2bf(float f) {
    union { float f; unsigned u; } v; v.f = f;
    unsigned r = v.u + 0x7FFFu + ((v.u >> 16) & 1u);  // RNE
    return (ushort_t)(r >> 16);
}
// pack two fp32 -> two bf16 (RNE): low half = bf(a), high = bf(b)
__device__ __forceinline__ unsigned pack2bf(float a, float b) {
    unsigned ua = __float_as_uint(a), ub = __float_as_uint(b);
    ua = ua + 0x7FFFu + ((ua >> 16) & 1u);
    ub = ub + 0x7FFFu + ((ub >> 16) & 1u);
    return __builtin_amdgcn_perm(ub, ua, 0x07060302);
}

// ---------- convert all fp32 inputs into one contiguous bf16 region ----------
__global__ __launch_bounds__(256) void convert_kernel(
    const float* __restrict__ x,  const float* __restrict__ wq, const float* __restrict__ bq_,
    const float* __restrict__ wk, const float* __restrict__ bk_, const float* __restrict__ wv,
    const float* __restrict__ bv_, const float* __restrict__ wo, const float* __restrict__ bo_,
    ushort_t* __restrict__ dst)
{
    const unsigned idx = ((unsigned)blockIdx.x * 256u + threadIdx.x) * 4u;
    if (idx >= CVT_TOT) return;
    const float* src; unsigned off;
    if      (idx < OFF_WQ) { src = x;   off = idx - OFF_X;  }
    else if (idx < OFF_BQ) { src = wq;  off = idx - OFF_WQ; }
    else if (idx < OFF_WK) { src = bq_; off = idx - OFF_BQ; }
    else if (idx < OFF_BK) { src = wk;  off = idx - OFF_WK; }
    else if (idx < OFF_WV) { src = bk_; off = idx - OFF_BK; }
    else if (idx < OFF_BV) { src = wv;  off = idx - OFF_WV; }
    else if (idx < OFF_WO) { src = bv_; off = idx - OFF_BV; }
    else if (idx < OFF_BO) { src = wo;  off = idx - OFF_WO; }
    else                   { src = bo_; off = idx - OFF_BO; }
    float4 v = *reinterpret_cast<const float4*>(src + off);
    uint2 p;
    p.x = pack2bf(v.x, v.y);
    p.y = pack2bf(v.z, v.w);
    *reinterpret_cast<uint2*>(dst + idx) = p;
}

// GEMM core, BK=64 via two unpadded [128][32] sub-tiles (m97 bank pattern,
// global_load_lds width-16). 32 MFMA per barrier pair, 16 iters at K=1024.
__device__ __forceinline__ void gemm_core(
    const ushort_t* __restrict__ X, const ushort_t* __restrict__ W,
    int m0, int n0, ushort_t* lds, floatx4 acc[4][4])
{
    const int tid = threadIdx.x;
    const int lane = tid & 63, wv = tid >> 6;
    const int wm = (wv >> 1) * 64, wn = (wv & 1) * 64;
    const int l15 = lane & 15, quad = lane >> 4;
    const floatx4 z4 = {0.f, 0.f, 0.f, 0.f};
#pragma unroll
    for (int i = 0; i < 4; ++i)
#pragma unroll
        for (int j = 0; j < 4; ++j) acc[i][j] = z4;
    const int lrow = lane >> 2;
    const int lcol = (lane & 3) * 8;
    const ushort_t* gA = X + (size_t)(m0 + lrow) * D_MODEL + lcol;
    const ushort_t* gB = W + (size_t)(n0 + lrow) * D_MODEL + lcol;
    for (int k0 = 0; k0 < D_MODEL; k0 += 64) {
        __syncthreads();
#pragma unroll
        for (int j = 0; j < 2; ++j) {
            const int r0 = (wv * 2 + j) * 16;
            __builtin_amdgcn_global_load_lds(
                (const AS1 unsigned*)(gA + (size_t)r0 * D_MODEL + k0),
                (AS3 unsigned*)(lds + r0 * 32), 16, 0, 0);
            __builtin_amdgcn_global_load_lds(
                (const AS1 unsigned*)(gA + (size_t)r0 * D_MODEL + k0 + 32),
                (AS3 unsigned*)(lds + 4096 + r0 * 32), 16, 0, 0);
            __builtin_amdgcn_global_load_lds(
                (const AS1 unsigned*)(gB + (size_t)r0 * D_MODEL + k0),
                (AS3 unsigned*)(lds + 8192 + r0 * 32), 16, 0, 0);
            __builtin_amdgcn_global_load_lds(
                (const AS1 unsigned*)(gB + (size_t)r0 * D_MODEL + k0 + 32),
                (AS3 unsigned*)(lds + 12288 + r0 * 32), 16, 0, 0);
        }
        asm volatile("s_waitcnt vmcnt(0)" ::: "memory");
        __syncthreads();
#pragma unroll
        for (int ks = 0; ks < 2; ++ks) {
            const ushort_t* A = lds + ks * 4096;
            const ushort_t* B = lds + 8192 + ks * 4096;
            bf16x8 af[4], bfr[4];
#pragma unroll
            for (int i = 0; i < 4; ++i)
                af[i] = *reinterpret_cast<const bf16x8*>(A + (wm + i * 16 + l15) * 32 + quad * 8);
#pragma unroll
            for (int j = 0; j < 4; ++j)
                bfr[j] = *reinterpret_cast<const bf16x8*>(B + (wn + j * 16 + l15) * 32 + quad * 8);
#pragma unroll
            for (int i = 0; i < 4; ++i)
#pragma unroll
                for (int j = 0; j < 4; ++j)
                    acc[i][j] = __builtin_amdgcn_mfma_f32_16x16x32_bf16(af[i], bfr[j], acc[i][j], 0, 0, 0);
        }
    }
}

// Fused QKV projection. grid = (32, 24). Q pre-scaled by log2(e)/8.
__global__ __launch_bounds__(256, 3) void qkv_kernel(
    const ushort_t* __restrict__ x,
    const ushort_t* __restrict__ Wq, const ushort_t* __restrict__ bq,
    const ushort_t* __restrict__ Wk, const ushort_t* __restrict__ bk,
    const ushort_t* __restrict__ Wv, const ushort_t* __restrict__ bv,
    ushort_t* __restrict__ q_ws, ushort_t* __restrict__ k_ws, ushort_t* __restrict__ vt_ws)
{
    __shared__ __align__(16) ushort_t lds[17408];
    const int m0 = blockIdx.x * 128;
    const int which = blockIdx.y >> 3;
    const int n0 = (blockIdx.y & 7) * 128;
    const ushort_t* W    = (which == 0) ? Wq : (which == 1) ? Wk : Wv;
    const ushort_t* bias = (which == 0) ? bq : (which == 1) ? bk : bv;
    floatx4 acc[4][4];
    gemm_core(x, W, m0, n0, lds, acc);
    const int tid = threadIdx.x, lane = tid & 63, wv = tid >> 6;
    const int wm = (wv >> 1) * 64, wn = (wv & 1) * 64;
    const int l15 = lane & 15, quad = lane >> 4;
    const int b0 = m0 >> 11;
    const int s0 = m0 & (SEQ - 1);
    __syncthreads();
    if (which < 2) {
        ushort_t* Ts = lds;  // [128 m][136 n]
        ushort_t* dst = (which == 0) ? q_ws : k_ws;
        const float scl = (which == 0) ? QSCALE : 1.0f;
#pragma unroll
        for (int j = 0; j < 4; ++j) {
            int coln = wn + j * 16 + l15;
            float bb = bf2f(bias[n0 + coln]);
#pragma unroll
            for (int i = 0; i < 4; ++i)
#pragma unroll
                for (int r = 0; r < 4; ++r) {
                    int rowm = wm + i * 16 + quad * 4 + r;
                    Ts[rowm * 136 + coln] = f2bf((acc[i][j][r] + bb) * scl);
                }
        }
        __syncthreads();
#pragma unroll
        for (int i = 0; i < 8; ++i) {
            int c = tid + 256 * i;
            int rowm = c >> 4, chunk = c & 15;
            float4 v = *reinterpret_cast<const float4*>(Ts + rowm * 136 + chunk * 8);
            int s = s0 + rowm;
            int n = n0 + chunk * 8, h = n >> 6, d = n & 63;
            *reinterpret_cast<float4*>(dst + (((size_t)(b0 * NH + h)) * SEQ + s) * DKH + d) = v;
        }
    } else {
        ushort_t* Ts = lds;  // [128 n][136 m]
#pragma unroll
        for (int j = 0; j < 4; ++j) {
            int coln = wn + j * 16 + l15;
            float bb = bf2f(bias[n0 + coln]);
#pragma unroll
            for (int i = 0; i < 4; ++i)
#pragma unroll
                for (int r = 0; r < 4; ++r) {
                    int rowm = wm + i * 16 + quad * 4 + r;
                    Ts[coln * 136 + rowm] = f2bf(acc[i][j][r] + bb);
                }
        }
        __syncthreads();
#pragma unroll
        for (int i = 0; i < 8; ++i) {
            int c = tid + 256 * i;
            int nr = c >> 4, mc = (c & 15) * 8;
            float4 v = *reinterpret_cast<const float4*>(Ts + nr * 136 + mc);
            int n = n0 + nr, h = n >> 6, d = n & 63;
            *reinterpret_cast<float4*>(vt_ws + (((size_t)(b0 * NH + h)) * DKH + d) * SEQ + s0 + mc) = v;
        }
    }
}

// Flash attention, round-11 composite of measured wins:
//  - BQ=128, 512 threads, in-block KV half-split (r6: staging economy)
//  - x32 PV via b64 P->LDS round-trip (r5-vs-r8 A/B: x16 reg-P costs ~+13 us)
//  - VGPR prefetch of tile t+1 before compute(t) (r10: hides global latency)
//  - vectorized la4 softmax accumulate (r10)
// grid = (16 q-tiles, 32 b*h). Each wave owns 32 q-rows over its KV half.
__global__ __launch_bounds__(512, 4) void attn_kernel(
    const ushort_t* __restrict__ q_ws, const ushort_t* __restrict__ k_ws,
    const ushort_t* __restrict__ vt_ws, ushort_t* __restrict__ concat)
{
    __shared__ __align__(16) ushort_t sm[36864];  // 73.7 KB -> 2 blocks/CU (grid-capped anyway)
    // [0,9216): K [half][64][72]; [9216,18432): V^T [half][64][72]
    // [18432,36864): P [8 waves][32][72]; transient Q staging [128][72]
    const int qb = blockIdx.x, bh = blockIdx.y;
    const int tid = threadIdx.x;
    const int lane = tid & 63, wv = tid >> 6;
    const int half = wv >> 2, wq = wv & 3;
    const int l15 = lane & 15, quad = lane >> 4;
    const int ht = tid & 255;  // thread id within half-group

    const ushort_t* Qg = q_ws + ((size_t)bh * SEQ + qb * 128) * DKH;
    const ushort_t* Kg = k_ws + ((size_t)bh * SEQ + half * (SEQ / 2)) * DKH;
    const ushort_t* Vg = vt_ws + (size_t)bh * DKH * SEQ + half * (SEQ / 2);

    ushort_t* Ks     = sm + half * 4608;
    ushort_t* VTs    = sm + 9216 + half * 4608;
    ushort_t* Ps     = sm + 18432 + wv * 2304;   // [32][72] per wave
    ushort_t* Qstage = sm + 18432;               // [128][72]

    // staging geometry: 512 chunks of 8 elts cover [64][64]; this thread owns 2
    const int r0c = ht >> 3,         c0c = (ht & 7) * 8;
    const int r1c = (ht + 256) >> 3, c1c = ((ht + 256) & 7) * 8;

    // stage Q [128][64] -> Qstage, pull B-fragments to registers
#pragma unroll
    for (int i = 0; i < 2; ++i) {
        int c = tid + 512 * i;
        int row = c >> 3, col = (c & 7) * 8;
        *reinterpret_cast<float4*>(Qstage + row * 72 + col) =
            *reinterpret_cast<const float4*>(Qg + row * DKH + col);
    }
    __syncthreads();
    bf16x8 aq[2][2];
#pragma unroll
    for (int nt = 0; nt < 2; ++nt)
#pragma unroll
        for (int ks = 0; ks < 2; ++ks)
            aq[nt][ks] = *reinterpret_cast<const bf16x8*>(Qstage + (wq * 32 + nt * 16 + l15) * 72 + ks * 32 + quad * 8);

    const floatx4 z4 = {0.f, 0.f, 0.f, 0.f};
    floatx4 o[2][4];
    floatx4 la4[2] = {z4, z4};
#pragma unroll
    for (int nt = 0; nt < 2; ++nt)
#pragma unroll
        for (int dt = 0; dt < 4; ++dt) o[nt][dt] = z4;

    // prologue: prefetch tile 0 into VGPRs
    float4 pk0 = *reinterpret_cast<const float4*>(Kg + (size_t)r0c * DKH + c0c);
    float4 pk1 = *reinterpret_cast<const float4*>(Kg + (size_t)r1c * DKH + c1c);
    float4 pv0 = *reinterpret_cast<const float4*>(Vg + (size_t)r0c * SEQ + c0c);
    float4 pv1 = *reinterpret_cast<const float4*>(Vg + (size_t)r1c * SEQ + c1c);

    for (int t = 0; t < 16; ++t) {
        __syncthreads();  // prior tile's MFMA reads of Ks/VTs done (covers Qstage reads at t=0)
        *reinterpret_cast<float4*>(Ks + r0c * 72 + c0c) = pk0;
        *reinterpret_cast<float4*>(Ks + r1c * 72 + c1c) = pk1;
        *reinterpret_cast<float4*>(VTs + r0c * 72 + c0c) = pv0;
        *reinterpret_cast<float4*>(VTs + r1c * 72 + c1c) = pv1;
        __syncthreads();
        if (t < 15) {  // prefetch next tile; retires during compute below
            int toff = (t + 1) * 64;
            pk0 = *reinterpret_cast<const float4*>(Kg + (size_t)(toff + r0c) * DKH + c0c);
            pk1 = *reinterpret_cast<const float4*>(Kg + (size_t)(toff + r1c) * DKH + c1c);
            pv0 = *reinterpret_cast<const float4*>(Vg + (size_t)r0c * SEQ + toff + c0c);
            pv1 = *reinterpret_cast<const float4*>(Vg + (size_t)r1c * SEQ + toff + c1c);
        }

        // S^T = K·Q^T : 64 kcols x 32 qrows per wave (x32 MFMA; akf shared across nt)
        floatx4 st[2][4];
#pragma unroll
        for (int nt = 0; nt < 2; ++nt)
#pragma unroll
            for (int mt = 0; mt < 4; ++mt) st[nt][mt] = z4;
#pragma unroll
        for (int ks = 0; ks < 2; ++ks)
#pragma unroll
            for (int mt = 0; mt < 4; ++mt) {
                bf16x8 akf = *reinterpret_cast<const bf16x8*>(Ks + (mt * 16 + l15) * 72 + ks * 32 + quad * 8);
                st[0][mt] = __builtin_amdgcn_mfma_f32_16x16x32_bf16(akf, aq[0][ks], st[0][mt], 0, 0, 0);
                st[1][mt] = __builtin_amdgcn_mfma_f32_16x16x32_bf16(akf, aq[1][ks], st[1][mt], 0, 0, 0);
            }

        // p = 2^s (log2 domain), vector l-accumulate, b64 P writes (wave-private rows)
#pragma unroll
        for (int nt = 0; nt < 2; ++nt)
#pragma unroll
            for (int mt = 0; mt < 4; ++mt) {
#pragma unroll
                for (int r = 0; r < 4; ++r) st[nt][mt][r] = exp2f(st[nt][mt][r]);
                la4[nt] += st[nt][mt];
                uint2 pk;
                pk.x = pack2bf(st[nt][mt][0], st[nt][mt][1]);
                pk.y = pack2bf(st[nt][mt][2], st[nt][mt][3]);
                *reinterpret_cast<uint2*>(Ps + (nt * 16 + l15) * 72 + mt * 16 + quad * 4) = pk;
            }
        asm volatile("s_waitcnt lgkmcnt(0)" ::: "memory");
        // O += P @ V  (x32 MFMA; bvv shared across nt)
#pragma unroll
        for (int ks = 0; ks < 2; ++ks) {
            bf16x8 ap0 = *reinterpret_cast<const bf16x8*>(Ps + l15 * 72 + ks * 32 + quad * 8);
            bf16x8 ap1 = *reinterpret_cast<const bf16x8*>(Ps + (16 + l15) * 72 + ks * 32 + quad * 8);
#pragma unroll
            for (int dt = 0; dt < 4; ++dt) {
                bf16x8 bvv = *reinterpret_cast<const bf16x8*>(VTs + (dt * 16 + l15) * 72 + ks * 32 + quad * 8);
                o[0][dt] = __builtin_amdgcn_mfma_f32_16x16x32_bf16(ap0, bvv, o[0][dt], 0, 0, 0);
                o[1][dt] = __builtin_amdgcn_mfma_f32_16x16x32_bf16(ap1, bvv, o[1][dt], 0, 0, 0);
            }
        }
    }
    // l per q-row (q = wq*32+nt*16+l15): sum la4 components + quad reduction
    float lsum[2];
#pragma unroll
    for (int nt = 0; nt < 2; ++nt) {
        float s = la4[nt][0] + la4[nt][1] + la4[nt][2] + la4[nt][3];
        s += __shfl_xor(s, 16, 64);
        s += __shfl_xor(s, 32, 64);
        lsum[nt] = s;
    }
    // merge halves (linear, no-max softmax): O = O0+O1, l = l0+l1 through LDS
    __syncthreads();
    float* Of = (float*)sm;        // [128 q][68 d]  (34816 B)
    float* lf = Of + 128 * 68;     // [128 q]        (35.3 KB <= 73.7 KB)
    if (half == 1) {
#pragma unroll
        for (int nt = 0; nt < 2; ++nt) {
            if (quad == 0) lf[wq * 32 + nt * 16 + l15] = lsum[nt];
#pragma unroll
            for (int r = 0; r < 4; ++r) {
                int row = wq * 32 + nt * 16 + quad * 4 + r;
#pragma unroll
                for (int dt = 0; dt < 4; ++dt)
                    Of[row * 68 + dt * 16 + l15] = o[nt][dt][r];
            }
        }
    }
    __syncthreads();
    if (half == 0) {
        const int b0 = bh >> 4, h = bh & 15;
#pragma unroll
        for (int nt = 0; nt < 2; ++nt) {
            float ltot = lsum[nt] + lf[wq * 32 + nt * 16 + l15];
            float linv = 1.f / ltot;
#pragma unroll
            for (int r = 0; r < 4; ++r) {
                float lB = __shfl(linv, quad * 4 + r, 64);
                int row = wq * 32 + nt * 16 + quad * 4 + r;
                size_t base = ((size_t)(b0 * SEQ + qb * 128 + row)) * D_MODEL + h * DKH;
#pragma unroll
                for (int dt = 0; dt < 4; ++dt) {
                    float sum = o[nt][dt][r] + Of[row * 68 + dt * 16 + l15];
                    concat[base + dt * 16 + l15] = f2bf(sum * lB);
                }
            }
        }
    }
}

// Output projection: out = concat @ Wo^T + bo. grid = (32, 8). fp32 output.
__global__ __launch_bounds__(256, 3) void oproj_kernel(
    const ushort_t* __restrict__ cc, const ushort_t* __restrict__ Wo,
    const ushort_t* __restrict__ bo, float* __restrict__ out)
{
    __shared__ __align__(16) ushort_t lds[4 * 128 * 32];
    const int m0 = blockIdx.x * 128, n0 = blockIdx.y * 128;
    floatx4 acc[4][4];
    gemm_core(cc, Wo, m0, n0, lds, acc);
    const int tid = threadIdx.x, lane = tid & 63, wv = tid >> 6;
    const int wm = (wv >> 1) * 64, wn = (wv & 1) * 64;
    const int l15 = lane & 15, quad = lane >> 4;
#pragma unroll
    for (int j = 0; j < 4; ++j) {
        int n = n0 + wn + j * 16 + l15;
        float bb = bf2f(bo[n]);
#pragma unroll
        for (int i = 0; i < 4; ++i)
#pragma unroll
            for (int r = 0; r < 4; ++r) {
                int m = m0 + wm + i * 16 + quad * 4 + r;
                out[(size_t)m * D_MODEL + n] = acc[i][j][r] + bb;
            }
    }
}

extern "C" void kernel_launch(void* const* d_in, const int* in_sizes, int n_in,
                              void* d_out, int out_size, void* d_ws, size_t ws_size,
                              hipStream_t stream)
{
    ushort_t* cvt = (ushort_t*)d_ws;
    const ushort_t* xb  = cvt + OFF_X;
    const ushort_t* Wqb = cvt + OFF_WQ;
    const ushort_t* bqb = cvt + OFF_BQ;
    const ushort_t* Wkb = cvt + OFF_WK;
    const ushort_t* bkb = cvt + OFF_BK;
    const ushort_t* Wvb = cvt + OFF_WV;
    const ushort_t* bvb = cvt + OFF_BV;
    const ushort_t* Wob = cvt + OFF_WO;
    const ushort_t* bob = cvt + OFF_BO;
    ushort_t* q_ws   = cvt + CVT_TOT;                        // [B,H,S,64] (Q pre-scaled)
    ushort_t* k_ws   = q_ws  + (size_t)MTOT * D_MODEL;       // [B,H,S,64]
    ushort_t* vt_ws  = k_ws  + (size_t)MTOT * D_MODEL;       // [B,H,64,S]
    ushort_t* concat = vt_ws + (size_t)MTOT * D_MODEL;       // [B,S,D]

    convert_kernel<<<(CVT_TOT / 1024), 256, 0, stream>>>(
        (const float*)d_in[0], (const float*)d_in[1], (const float*)d_in[2],
        (const float*)d_in[3], (const float*)d_in[4], (const float*)d_in[5],
        (const float*)d_in[6], (const float*)d_in[7], (const float*)d_in[8], cvt);
    qkv_kernel<<<dim3(32, 24), 256, 0, stream>>>(xb, Wqb, bqb, Wkb, bkb, Wvb, bvb, q_ws, k_ws, vt_ws);
    attn_kernel<<<dim3(16, 32), 512, 0, stream>>>(q_ws, k_ws, vt_ws, concat);
    oproj_kernel<<<dim3(32, 8), 256, 0, stream>>>(concat, Wob, bob, (float*)d_out);
}